// Round 10
// baseline (248.291 us; speedup 1.0000x reference)
//
#include <hip/hip_runtime.h>
#include <hip/hip_bf16.h>
#include <math.h>

// Problem constants
#define TDIM 4096
#define CDIM 256
#define BDIM 8
#define NTOK (BDIM * TDIM)   // 32768 rows
#define HIDDIM 1024
#define NCHUNK 256
#define CHLEN 16             // 4096 / 256
#define NSEG 8
#define SEGCH 32             // NCHUNK / NSEG

typedef float f32x4 __attribute__((ext_vector_type(4)));
typedef __bf16 bf16x8 __attribute__((ext_vector_type(8)));
typedef __bf16 bf16x4 __attribute__((ext_vector_type(4)));
typedef long long i64x2 __attribute__((ext_vector_type(2)));

// async global->LDS, 16 B/lane, lands at wave-uniform base + lane*16
#define GLDS16(gp, lp) __builtin_amdgcn_global_load_lds( \
    (const __attribute__((address_space(1))) void*)(gp), \
    (__attribute__((address_space(3))) void*)(lp), 16, 0, 0)

// s_waitcnt imm: vmcnt[3:0] in [3:0], expcnt [6:4], lgkm in [11:8], vmcnt[5:4] in [15:14]
#define WAITCNT_VM8  0x0F78
#define WAITCNT_VM5  0x0F75
#define WAITCNT_VM4  0x0F74
#define WAITCNT_VM2  0x0F72
#define WAITCNT_VM0  0x0F70
#define WAITCNT_LGKM0 0xC07F   // lgkmcnt(0) only; vmcnt/expcnt unconstrained

// LDS producer->consumer fence across waves: ds_writes must LAND before the
// barrier (raw s_barrier does NOT drain lgkmcnt — the r5 race).
#define STAGE_FENCE() do { \
    __builtin_amdgcn_sched_barrier(0); \
    __builtin_amdgcn_s_waitcnt(WAITCNT_LGKM0); \
    __builtin_amdgcn_s_barrier(); \
    __builtin_amdgcn_sched_barrier(0); \
  } while (0)

__device__ __forceinline__ float sigm(float v) { return 1.0f / (1.0f + __expf(-v)); }

// fp8 k-permutation within each 64-k group: k = p*64 + c*32 + q*8 + j
// -> byte position p*64 + q*16 + c*8 + j. A lane's b128 at row*64+q*16 then
// holds [chunk0 frag | chunk1 frag] for MFMA k=quad*8..+8 of both 32-chunks.
__device__ __forceinline__ int permk(int k) {
  return (k & ~63) + (((k >> 3) & 3) << 4) + (((k >> 5) & 1) << 3) + (k & 7);
}

// ---------------------------------------------------------------------------
// prep: merged weight-pack (blocks 0..1023) + LayerNorm1 (blocks 1024..9215).
// ---------------------------------------------------------------------------
__global__ __launch_bounds__(256) void prep(
    const float* __restrict__ Wk, const float* __restrict__ Wv,
    const float* __restrict__ Wr, const float* __restrict__ Wo,
    const float* __restrict__ Wkf, const float* __restrict__ Wvf,
    const float* __restrict__ Wrf,
    __bf16* __restrict__ WoT, unsigned char* __restrict__ Wkvr8,
    unsigned char* __restrict__ Wkfr8, unsigned char* __restrict__ Wvf8,
    const float* __restrict__ x, const float* __restrict__ gamma,
    const float* __restrict__ beta, unsigned char* __restrict__ h8) {
  if (blockIdx.x >= 1024) {
    // ---- LayerNorm over C=256: one wave per row ----
    const int wave = threadIdx.x >> 6, lane = threadIdx.x & 63;
    const long long row = (long long)(blockIdx.x - 1024) * 4 + wave;
    const long long base = row * CDIM + lane * 4;
    const f32x4 v = *(const f32x4*)&x[base];
    float s = v[0] + v[1] + v[2] + v[3];
    float s2 = v[0]*v[0] + v[1]*v[1] + v[2]*v[2] + v[3]*v[3];
    #pragma unroll
    for (int o = 1; o < 64; o <<= 1) { s += __shfl_xor(s, o); s2 += __shfl_xor(s2, o); }
    const float mean = s * (1.0f / CDIM);
    const float var = s2 * (1.0f / CDIM) - mean * mean;
    const float rstd = rsqrtf(var + 1e-5f);
    const f32x4 g4 = *(const f32x4*)&gamma[lane * 4];
    const f32x4 b4 = *(const f32x4*)&beta[lane * 4];
    float o0 = (v[0] - mean) * rstd * g4[0] + b4[0];
    float o1 = (v[1] - mean) * rstd * g4[1] + b4[1];
    float o2 = (v[2] - mean) * rstd * g4[2] + b4[2];
    float o3 = (v[3] - mean) * rstd * g4[3] + b4[3];
    int w = 0;
    w = __builtin_amdgcn_cvt_pk_fp8_f32(o0, o1, w, false);
    w = __builtin_amdgcn_cvt_pk_fp8_f32(o2, o3, w, true);
    *(int*)&h8[row * CDIM + permk(lane * 4)] = w;
    return;
  }
  long long j = (long long)blockIdx.x * 256 + threadIdx.x;
  if (j < 49152) {            // Wkvr8: 4 fp8/thread
    const long long d = j * 4;
    const int n = (int)(d >> 8), k0 = (int)(d & 255);
    const float* src = (n < 256) ? Wk : (n < 512 ? Wv : Wr);
    const int nn = n & 255;
    int w = 0;
    w = __builtin_amdgcn_cvt_pk_fp8_f32(src[k0 * 256 + nn],
                                        src[(k0 + 1) * 256 + nn], w, false);
    w = __builtin_amdgcn_cvt_pk_fp8_f32(src[(k0 + 2) * 256 + nn],
                                        src[(k0 + 3) * 256 + nn], w, true);
    *(int*)&Wkvr8[(long long)n * 256 + permk(k0)] = w;
    return;
  }
  j -= 49152;
  if (j < 65536) { int n = (int)(j >> 8), k = (int)(j & 255);
    WoT[j] = (__bf16)Wo[k * 256 + n]; return; }
  j -= 65536;
  if (j < 81920) {            // Wkfr8: 4 fp8/thread
    const long long d = j * 4;
    const int n = (int)(d >> 8), k0 = (int)(d & 255);
    float v0, v1, v2, v3;
    if (n < 1024) {
      v0 = Wkf[(long long)k0 * 1024 + n];       v1 = Wkf[(long long)(k0 + 1) * 1024 + n];
      v2 = Wkf[(long long)(k0 + 2) * 1024 + n]; v3 = Wkf[(long long)(k0 + 3) * 1024 + n];
    } else {
      const int m = n - 1024;
      v0 = Wrf[k0 * 256 + m];       v1 = Wrf[(k0 + 1) * 256 + m];
      v2 = Wrf[(k0 + 2) * 256 + m]; v3 = Wrf[(k0 + 3) * 256 + m];
    }
    int w = 0;
    w = __builtin_amdgcn_cvt_pk_fp8_f32(v0, v1, w, false);
    w = __builtin_amdgcn_cvt_pk_fp8_f32(v2, v3, w, true);
    *(int*)&Wkfr8[(long long)n * 256 + permk(k0)] = w;
    return;
  }
  j -= 81920;
  if (j < 65536) {            // Wvf8 [256][1024]: 4 fp8/thread
    const long long d = j * 4;
    const int n = (int)(d >> 10), k0 = (int)(d & 1023);
    int w = 0;
    w = __builtin_amdgcn_cvt_pk_fp8_f32(Wvf[(long long)k0 * 256 + n],
                                        Wvf[(long long)(k0 + 1) * 256 + n], w, false);
    w = __builtin_amdgcn_cvt_pk_fp8_f32(Wvf[(long long)(k0 + 2) * 256 + n],
                                        Wvf[(long long)(k0 + 3) * 256 + n], w, true);
    *(int*)&Wvf8[(long long)n * 1024 + permk(k0)] = w;
    return;
  }
}

// ---------------------------------------------------------------------------
// gemmF: K=256 fp8 GEMM, tile-streaming persistent structure.
//   NEW (r10): T2 XOR-swizzle on sA to kill the 8-way ds_read_b128 bank
//   conflict (bank = (row&1)<<4|quad<<2 -> 8 rows per bank-group). 16B chunk
//   c at row r lives at c ^ ((r>>1)&3). Staged rows start at multiples of 16,
//   so: GLDS16 SOURCE offset (lane&3)->(lane&3)^((lane>>3)&3) (LDS dest stays
//   linear — m104 rule), ds_read chunk quad->quad^((mrow>>1)&3).
// ---------------------------------------------------------------------------
template <int EPI, int NY>
__global__ __launch_bounds__(512, 4) void gemmF(
    const unsigned char* __restrict__ A8, const unsigned char* __restrict__ B8,
    __bf16* __restrict__ outH, __bf16* __restrict__ outH2,
    unsigned char* __restrict__ outC) {
  constexpr int NTILES = 256 * NY;
  constexpr int TPB = NTILES / 512;
  static_assert(NTILES % 512 == 0, "grid divisibility");
  __shared__ unsigned char sA[2][4 * 8192];   // [buf][granule g][row 0..127][64B]

  const int tid = threadIdx.x;
  const int wave = tid >> 6, lane = tid & 63;
  const int quad = lane >> 4, mrow = lane & 15;
  const int wm = (wave & 1) * 64, wn = (wave >> 1) * 32;
  const int srow = lane >> 2;          // 0..15 (4 lanes per 64-B granule row)
  const int o16s = (((lane & 3) ^ ((lane >> 3) & 3)) << 4);  // swizzled source chunk
  const int rsw = (mrow >> 1) & 3;     // read-side swizzle
  const int t0 = blockIdx.x * TPB;

  auto issueA = [&](int t, int buf) {
    const long long bm = (long long)(t & 255) * 128;
    const int r0 = wave * 16;
    #pragma unroll
    for (int g = 0; g < 4; g++)
      GLDS16(A8 + (bm + r0 + srow) * 256 + g * 64 + o16s,
             &sA[buf][g * 8192 + r0 * 64]);
  };

  // B panel in registers: 8 x b128 per wave (2 nt x 4 granules)
  i64x2 fb[2][4];
  auto loadB = [&](int y) {
    const long long bn = (long long)y * 128;
    #pragma unroll
    for (int nt = 0; nt < 2; nt++)
      #pragma unroll
      for (int g = 0; g < 4; g++)
        fb[nt][g] = *(const i64x2*)
            &B8[(bn + wn + nt * 16 + mrow) * 256 + g * 64 + quad * 16];
  };

  issueA(t0, 0);
  int prevy = -1;

  #pragma unroll 1
  for (int i = 0; i < TPB; i++) {
    const int t = t0 + i;
    const int y = t >> 8;
    const bool ych = (y != prevy);
    prevy = y;

    // A(t) landed (oldest vmem ops); prior-tile stores may stay in flight.
    if (i == 0)          __builtin_amdgcn_s_waitcnt(WAITCNT_VM0);
    else if (EPI == 0)   __builtin_amdgcn_s_waitcnt(WAITCNT_VM4);
    else                 __builtin_amdgcn_s_waitcnt(WAITCNT_VM2);
    __builtin_amdgcn_s_barrier();

    if (ych) loadB(y);                       // rare (y-panel boundary)
    if (i + 1 < TPB) issueA(t + 1, (i + 1) & 1);

    // ---- compute: full K=256 in one pass, 64 MFMA/wave ----
    f32x4 acc[4][2] = {};
    const int buf = i & 1;
    #pragma unroll
    for (int g = 0; g < 4; g++) {
      i64x2 fa[4];
      #pragma unroll
      for (int mt = 0; mt < 4; mt++)
        fa[mt] = *(const i64x2*)
            &sA[buf][g * 8192 + (wm + mt * 16 + mrow) * 64 + ((quad ^ rsw) << 4)];
      #pragma unroll
      for (int c = 0; c < 2; c++)
        #pragma unroll
        for (int mt = 0; mt < 4; mt++)
          #pragma unroll
          for (int nt = 0; nt < 2; nt++)
            acc[mt][nt] = __builtin_amdgcn_mfma_f32_16x16x32_fp8_fp8(
                fb[nt][g][c], fa[mt][c], acc[mt][nt], 0, 0, 0);
    }

    // ---- staged epilogue: sA[buf] is dead; reuse as output staging ----
    __builtin_amdgcn_s_barrier();
    unsigned char* stg = &sA[buf][0];
    const long long bm = (long long)(t & 255) * 128;

    if (EPI == 0) {
      const int plane = y >> 1;
      // stage: [128 rows][256B bf16], XOR-swizzled 16B chunks
      #pragma unroll
      for (int mt = 0; mt < 4; mt++) {
        const int row = wm + mt * 16 + mrow;
        const int swz = (row & 7) << 4;
        #pragma unroll
        for (int nt = 0; nt < 2; nt++) {
          const f32x4 a = acc[mt][nt];
          bf16x4 v;
          if (plane == 2) {
            #pragma unroll
            for (int r = 0; r < 4; r++) v[r] = (__bf16)sigm(a[r]);
          } else {
            #pragma unroll
            for (int r = 0; r < 4; r++) v[r] = (__bf16)a[r];
          }
          const int cb2 = (wn + nt * 16 + quad * 4) * 2;
          *(bf16x4*)&stg[row * 256 + (cb2 ^ swz)] = v;
        }
      }
      STAGE_FENCE();
      // write-out: 512 threads x 64B contiguous
      char* ob = (char*)(outH + (long long)plane * (32768LL * 256));
      const int row = tid >> 2, qb = (tid & 3) * 64;
      const int swz = (row & 7) << 4;
      const long long gb = (bm + row) * 512 + (long long)(y & 1) * 256 + qb;
      #pragma unroll
      for (int c = 0; c < 4; c++) {
        const i64x2 d = *(const i64x2*)&stg[row * 256 + ((qb + c * 16) ^ swz)];
        *(i64x2*)&ob[gb + c * 16] = d;
      }
    } else {
      if (y < 8) {
        // stage: [128 rows][128B fp8], permk within row, XOR-swizzled
        #pragma unroll
        for (int mt = 0; mt < 4; mt++) {
          const int row = wm + mt * 16 + mrow;
          const int swz = (row & 7) << 4;
          #pragma unroll
          for (int nt = 0; nt < 2; nt++) {
            const f32x4 a = acc[mt][nt];
            float q0 = a[0] > 0.0f ? a[0] : 0.0f;
            float q1 = a[1] > 0.0f ? a[1] : 0.0f;
            float q2 = a[2] > 0.0f ? a[2] : 0.0f;
            float q3 = a[3] > 0.0f ? a[3] : 0.0f;
            int w = 0;
            w = __builtin_amdgcn_cvt_pk_fp8_f32(q0 * q0, q1 * q1, w, false);
            w = __builtin_amdgcn_cvt_pk_fp8_f32(q2 * q2, q3 * q3, w, true);
            const int cbl = wn + nt * 16 + quad * 4;      // tile-local col
            *(int*)&stg[row * 128 + (permk(cbl) ^ swz)] = w;
          }
        }
        STAGE_FENCE();
        // write-out: 512 threads x 32B contiguous
        const int row = tid >> 2, sb = (tid & 3) * 32;
        const int swz = (row & 7) << 4;
        const long long gb = (bm + row) * 1024 + (long long)y * 128 + sb;
        #pragma unroll
        for (int c = 0; c < 2; c++) {
          const i64x2 d = *(const i64x2*)&stg[row * 128 + ((sb + c * 16) ^ swz)];
          *(i64x2*)&outC[gb + c * 16] = d;
        }
      } else {
        // stage: [128 rows][256B bf16]
        #pragma unroll
        for (int mt = 0; mt < 4; mt++) {
          const int row = wm + mt * 16 + mrow;
          const int swz = (row & 7) << 4;
          #pragma unroll
          for (int nt = 0; nt < 2; nt++) {
            const f32x4 a = acc[mt][nt];
            bf16x4 v;
            #pragma unroll
            for (int r = 0; r < 4; r++) v[r] = (__bf16)sigm(a[r]);
            const int cb2 = (wn + nt * 16 + quad * 4) * 2;
            *(bf16x4*)&stg[row * 256 + (cb2 ^ swz)] = v;
          }
        }
        STAGE_FENCE();
        char* ob = (char*)outH2;
        const int row = tid >> 2, qb = (tid & 3) * 64;
        const int swz = (row & 7) << 4;
        const long long gb = (bm + row) * 512 + (long long)(y - 8) * 256 + qb;
        #pragma unroll
        for (int c = 0; c < 4; c++) {
          const i64x2 d = *(const i64x2*)&stg[row * 256 + ((qb + c * 16) ^ swz)];
          *(i64x2*)&ob[gb + c * 16] = d;
        }
      }
    }
  }
}

// ---------------------------------------------------------------------------
// fp8 MFMA GEMM with k-permuted operands (K=1024, EPI 3 only).
// r10: same T2 swizzle on sA and sB (rows start at multiples of 16).
// ---------------------------------------------------------------------------
template <int K, int EPI>
__global__ __launch_bounds__(256, 3) void gemm9(
    const unsigned char* __restrict__ A8, const unsigned char* __restrict__ B8,
    int M, __bf16* __restrict__ outH, __bf16* __restrict__ outH2,
    unsigned char* __restrict__ outC,
    float* __restrict__ outF, const __bf16* __restrict__ srcH,
    const __bf16* __restrict__ gate) {
  constexpr int NIT = K / 64;
  __shared__ unsigned char sA[3][128 * 64];
  __shared__ unsigned char sB[3][128 * 64];
  const int tid = threadIdx.x;
  const int wave = tid >> 6, lane = tid & 63;
  const int quad = lane >> 4, mrow = lane & 15;
  const long long bm = (long long)blockIdx.x * 128;
  const long long bn = (long long)blockIdx.y * 128;
  const int wm = (wave & 1) * 64, wn = (wave >> 1) * 64;
  const int srow = lane >> 2;          // 0..15 (4 lanes per 64-B row)
  const int o16s = (((lane & 3) ^ ((lane >> 3) & 3)) << 4);
  const int rsw = (mrow >> 1) & 3;

  auto issue = [&](int g) {
    const int buf = g % 3;
    const long long k0 = (long long)g * 64;
    const int a0 = wave * 32;
    GLDS16(A8 + (bm + a0 + srow) * (long long)K + k0 + o16s, &sA[buf][a0 * 64]);
    GLDS16(A8 + (bm + a0 + 16 + srow) * (long long)K + k0 + o16s, &sA[buf][(a0 + 16) * 64]);
    GLDS16(B8 + (bn + a0 + srow) * (long long)K + k0 + o16s, &sB[buf][a0 * 64]);
    GLDS16(B8 + (bn + a0 + 16 + srow) * (long long)K + k0 + o16s, &sB[buf][(a0 + 16) * 64]);
  };

  f32x4 acc[4][4] = {};
  issue(0);
  if (NIT > 1) issue(1);

  auto compute = [&](int g) {
    const int buf = g % 3;
    i64x2 fa[4], fb[4];
    #pragma unroll
    for (int mt = 0; mt < 4; mt++)
      fa[mt] = *(const i64x2*)&sA[buf][(wm + mt * 16 + mrow) * 64 + ((quad ^ rsw) << 4)];
    #pragma unroll
    for (int nt = 0; nt < 4; nt++)
      fb[nt] = *(const i64x2*)&sB[buf][(wn + nt * 16 + mrow) * 64 + ((quad ^ rsw) << 4)];
    #pragma unroll
    for (int c = 0; c < 2; c++)
      #pragma unroll
      for (int mt = 0; mt < 4; mt++)
        #pragma unroll
        for (int nt = 0; nt < 4; nt++)
          acc[mt][nt] = __builtin_amdgcn_mfma_f32_16x16x32_fp8_fp8(
              fb[nt][c], fa[mt][c], acc[mt][nt], 0, 0, 0);
  };

  #pragma unroll 1
  for (int g = 0; g < NIT; g++) {
    if (g == NIT - 1) {
      __builtin_amdgcn_s_waitcnt(WAITCNT_VM0);
    } else {
      __builtin_amdgcn_s_waitcnt(WAITCNT_VM4);
    }
    __builtin_amdgcn_s_barrier();
    if (g + 2 < NIT) issue(g + 2);
    compute(g);
  }

  #pragma unroll
  for (int mt = 0; mt < 4; mt++) {
    #pragma unroll
    for (int nt = 0; nt < 4; nt++) {
      const long long row = bm + wm + mt * 16 + mrow;
      const long long colb = bn + wn + nt * 16 + quad * 4;
      const f32x4 a = acc[mt][nt];
      const long long idx = row * 256 + colb;
      const bf16x4 s4 = *(const bf16x4*)&srcH[idx];
      const bf16x4 g4 = *(const bf16x4*)&gate[idx];
      f32x4 v;
      #pragma unroll
      for (int r = 0; r < 4; r++) v[r] = (float)s4[r] + (float)g4[r] * a[r];
      *(f32x4*)&outF[idx] = v;
    }
  }
}

// ---------------------------------------------------------------------------
// WKV phases 1 & 2a — identical to r7/r9 (passing).
// ---------------------------------------------------------------------------
__global__ __launch_bounds__(256) void wkv_phase1(
    const __bf16* __restrict__ ka, const __bf16* __restrict__ va,
    const float* __restrict__ decay,
    float* __restrict__ Sloc, float* __restrict__ Zloc) {
  const int wave = threadIdx.x >> 6, lane = threadIdx.x & 63;
  const int gi = blockIdx.x * 4 + wave;          // 0..2047
  const int b = gi >> 8, chunk = gi & (NCHUNK - 1);
  const int c0 = lane * 4;
  const f32x4 w4 = *(const f32x4*)&decay[c0];
  f32x4 ew;
  #pragma unroll
  for (int r = 0; r < 4; r++) ew[r] = __expf(w4[r] * (1.0f / TDIM));
  f32x4 S = {0,0,0,0}, Z = {0,0,0,0};
  long long base = ((long long)b * TDIM + (long long)chunk * CHLEN) * 256 + c0;
  #pragma unroll 4
  for (int t = 0; t < CHLEN; t++) {
    const bf16x4 k4 = *(const bf16x4*)&ka[base + (long long)t * 256];
    const bf16x4 v4 = *(const bf16x4*)&va[base + (long long)t * 256];
    #pragma unroll
    for (int r = 0; r < 4; r++) {
      const float ek = __expf((float)k4[r]);
      S[r] = ew[r] * S[r] + ek * (float)v4[r];
      Z[r] = ew[r] * Z[r] + ek;
    }
  }
  const long long o = (long long)gi * 256 + c0;
  *(f32x4*)&Sloc[o] = S;
  *(f32x4*)&Zloc[o] = Z;
}

__global__ __launch_bounds__(256) void wkv_phase2a(
    const float* __restrict__ Sloc, const float* __restrict__ Zloc,
    const float* __restrict__ decay,
    float* __restrict__ LprefS, float* __restrict__ LprefZ,
    float* __restrict__ TS, float* __restrict__ TZ) {
  const int b = blockIdx.x >> 3, seg = blockIdx.x & 7;   // 64 blocks
  const int c = threadIdx.x;                             // one channel/thread
  const float w = decay[c] * (1.0f / TDIM);
  const float ewL = __expf(w * (float)CHLEN);
  float S = 0.0f, Z = 0.0f;
  long long o = ((long long)(b * NCHUNK + seg * SEGCH)) * 256 + c;
  #pragma unroll 4
  for (int i = 0; i < SEGCH; i++, o += 256) {
    LprefS[o] = S;
    LprefZ[o] = Z;
    S = ewL * S + Sloc[o];
    Z = ewL * Z + Zloc[o];
  }
  const int to = (b * NSEG + seg) * 256 + c;
  TS[to] = S;
  TZ[to] = Z;
}

// ---------------------------------------------------------------------------
// wkv3_gemm7: FUSED wkv_phase3 + gemm7 (r9 structure, passing).
//   r10: T2 swizzle on sB (GLDS source + read) and sA2 (ds_write + ds_read).
//   sA2 16B-chunk c at row r lives at c ^ ((r>>1)&3); write rows are
//   wave*16+t -> swz=(t>>1)&3; read rows mt*16+mrow -> swz=(mrow>>1)&3.
// ---------------------------------------------------------------------------
__global__ __launch_bounds__(256, 2) void wkv3_gemm7(
    const __bf16* __restrict__ ka, const __bf16* __restrict__ va,
    const __bf16* __restrict__ ra,   // holds sigmoid(r)
    const float* __restrict__ decay, const float* __restrict__ first,
    const float* __restrict__ LprefS, const float* __restrict__ LprefZ,
    const float* __restrict__ TS, const float* __restrict__ TZ,
    const __bf16* __restrict__ Bt,   // WoT [256][256]
    const float* __restrict__ x,
    const float* __restrict__ gammaP, const float* __restrict__ betaP,
    __bf16* __restrict__ x1h, unsigned char* __restrict__ h28) {
  __shared__ __bf16 sA2[8 * 64 * 32];         // 32 KB, [g][row][32 bf16]
  __shared__ __bf16 sB[2][256 * 32];          // 32 KB
  __shared__ float redS[4][64], redQ[4][64];  // 2 KB

  const int tid = threadIdx.x;
  const int wave = tid >> 6, lane = tid & 63;
  const int quad = lane >> 4, mrow = lane & 15;
  const long long bm = (long long)blockIdx.x * 64;
  const int wn = wave * 64;
  const int lrow = lane >> 2;
  const int lks = ((lane & 3) ^ ((lane >> 3) & 3)) * 8;   // swizzled src (bf16 units)
  const int rsw = (mrow >> 1) & 3;

  // B staging (WoT only; A comes from LDS)
  auto issue = [&](int g) {
    const int buf = g & 1;
    const long long k0 = (long long)g * 32;
    #pragma unroll
    for (int bc = 0; bc < 4; bc++) {
      const int r0 = wave * 64 + bc * 16;
      GLDS16(Bt + (r0 + lrow) * 256 + k0 + lks, &sB[buf][r0 * 32]);
    }
  };
  issue(0);    // lands during Phase A

  // ===== Phase A: WKV output pass for this wave's chunk -> sA2 =====
  {
    const int gi = blockIdx.x * 4 + wave;          // 0..2047
    const int b = gi >> 8, chunk = gi & (NCHUNK - 1);
    const int seg = chunk >> 5, d = chunk & (SEGCH - 1);
    const int c0 = lane * 4;
    const f32x4 w4 = *(const f32x4*)&decay[c0];
    const f32x4 u4 = *(const f32x4*)&first[c0];
    f32x4 ew, eu;
    #pragma unroll
    for (int r = 0; r < 4; r++) {
      ew[r] = __expf(w4[r] * (1.0f / TDIM));
      eu[r] = __expf(u4[r] * (1.0f / TDIM));
    }
    const long long so = (long long)gi * 256 + c0;
    const f32x4 Lp = *(const f32x4*)&LprefS[so];
    const f32x4 LpZ = *(const f32x4*)&LprefZ[so];
    f32x4 S, Z;
    #pragma unroll
    for (int r = 0; r < 4; r++) {
      const float wr = w4[r] * (1.0f / TDIM);
      const float ew32 = __expf(wr * (float)(CHLEN * SEGCH));
      float CS = 0.0f, CZ = 0.0f;
      const int tb = b * NSEG * 256 + c0 + r;
      for (int s = 0; s < seg; s++) {
        CS = ew32 * CS + TS[tb + s * 256];
        CZ = ew32 * CZ + TZ[tb + s * 256];
      }
      const float f0 = __expf(wr * (float)(CHLEN * d));
      S[r] = f0 * CS + Lp[r];
      Z[r] = f0 * CZ + LpZ[r];
    }
    long long gbase = ((long long)b * TDIM + (long long)chunk * CHLEN) * 256 + c0;
    // granule-major LDS target: granule = lane>>3; 16B chunk = (lane>>1)&3,
    // 8B half = lane&1; swizzled chunk position = chunk ^ ((t>>1)&3).
    const int abase = (lane >> 3) * 2048 + (wave * 16) * 32;
    const int cch = (lane >> 1) & 3;
    const int half4 = (lane & 1) * 4;
    #pragma unroll 2
    for (int t = 0; t < CHLEN; t++) {
      const long long p = gbase + (long long)t * 256;
      const bf16x4 k4 = *(const bf16x4*)&ka[p];
      const bf16x4 v4 = *(const bf16x4*)&va[p];
      const bf16x4 r4 = *(const bf16x4*)&ra[p];
      bf16x4 o;
      #pragma unroll
      for (int r = 0; r < 4; r++) {
        const float ek = __expf((float)k4[r]);
        const float E = eu[r] * ek;
        const float y = (S[r] + E * (float)v4[r]) / (Z[r] + E);
        o[r] = (__bf16)((float)r4[r] * y);
        S[r] = ew[r] * S[r] + ek * (float)v4[r];
        Z[r] = ew[r] * Z[r] + ek;
      }
      *(bf16x4*)&sA2[abase + t * 32 + ((cch ^ ((t >> 1) & 3)) * 8 + half4)] = o;
    }
  }
  __syncthreads();   // full fence: sA2 visible to all waves

  // ===== Phase B: gemm7 K-loop (A from sA2, B from GLDS-staged sB) =====
  f32x4 acc[4][4] = {};

  auto compute = [&](int g) {
    const int buf = g & 1;
    bf16x8 fa[4], fb[4];
    #pragma unroll
    for (int mt = 0; mt < 4; mt++)
      fa[mt] = *(const bf16x8*)&sA2[g * 2048 + (mt * 16 + mrow) * 32 + (quad ^ rsw) * 8];
    #pragma unroll
    for (int nt = 0; nt < 4; nt++)
      fb[nt] = *(const bf16x8*)&sB[buf][(wn + nt * 16 + mrow) * 32 + (quad ^ rsw) * 8];
    #pragma unroll
    for (int mt = 0; mt < 4; mt++)
      #pragma unroll
      for (int nt = 0; nt < 4; nt++)
        acc[mt][nt] = __builtin_amdgcn_mfma_f32_16x16x32_bf16(fb[nt], fa[mt], acc[mt][nt], 0, 0, 0);
  };

  #pragma unroll 1
  for (int g = 0; g < 8; g++) {
    __builtin_amdgcn_s_waitcnt(WAITCNT_VM0);   // issue(g) landed (posted 1 iter ago)
    __builtin_amdgcn_s_barrier();              // all waves done reading buf (g+1)&1
    if (g + 1 < 8) issue(g + 1);
    compute(g);
  }

  // residual add + LN partials
  float sum[4] = {0, 0, 0, 0}, sq[4] = {0, 0, 0, 0};
  #pragma unroll
  for (int mt = 0; mt < 4; mt++) {
    #pragma unroll
    for (int nt = 0; nt < 4; nt++) {
      const long long row = bm + mt * 16 + mrow;
      const long long colb = wn + nt * 16 + quad * 4;
      acc[mt][nt] += *(const f32x4*)&x[row * 256 + colb];
      #pragma unroll
      for (int r = 0; r < 4; r++) {
        sum[mt] += acc[mt][nt][r];
        sq[mt] += acc[mt][nt][r] * acc[mt][nt][r];
      }
    }
  }
  #pragma unroll
  for (int mt = 0; mt < 4; mt++) {
    sum[mt] += __shfl_xor(sum[mt], 16); sq[mt] += __shfl_xor(sq[mt], 16);
    sum[mt] += __shfl_xor(sum[mt], 32); sq[mt] += __shfl_xor(sq[mt], 32);
  }
  if (quad == 0) {
    #pragma unroll
    for (int mt = 0; mt < 4; mt++) {
      redS[wave][mt * 16 + mrow] = sum[mt];
      redQ[wave][mt * 16 + mrow] = sq[mt];
    }
  }
  __syncthreads();
  #pragma unroll
  for (int mt = 0; mt < 4; mt++) {
    const int rb = mt * 16 + mrow;
    const float ts = redS[0][rb] + redS[1][rb] + redS[2][rb] + redS[3][rb];
    const float tq = redQ[0][rb] + redQ[1][rb] + redQ[2][rb] + redQ[3][rb];
    const float mean = ts * (1.0f / 256.0f);
    const float rstd = rsqrtf(tq * (1.0f / 256.0f) - mean * mean + 1e-5f);
    const long long row = bm + rb;
    #pragma unroll
    for (int nt = 0; nt < 4; nt++) {
      const long long colb = wn + nt * 16 + quad * 4;
      const f32x4 g4 = *(const f32x4*)&gammaP[colb];
      const f32x4 b4 = *(const f32x4*)&betaP[colb];
      bf16x4 xo;
      const float t0 = acc[mt][nt][0], t1 = acc[mt][nt][1];
      const float t2 = acc[mt][nt][2], t3 = acc[mt][nt][3];
      xo[0] = (__bf16)t0; xo[1] = (__bf16)t1; xo[2] = (__bf16)t2; xo[3] = (__bf16)t3;
      const float h0 = (t0 - mean) * rstd * g4[0] + b4[0];
      const float h1 = (t1 - mean) * rstd * g4[1] + b4[1];
      const float h2v = (t2 - mean) * rstd * g4[2] + b4[2];
      const float h3 = (t3 - mean) * rstd * g4[3] + b4[3];
      *(bf16x4*)&x1h[row * 256 + colb] = xo;
      int w = 0;
      w = __builtin_amdgcn_cvt_pk_fp8_f32(h0, h1, w, false);
      w = __builtin_amdgcn_cvt_pk_fp8_f32(h2v, h3, w, true);
      *(int*)&h28[row * 256 + permk((int)colb)] = w;
    }
  }
}

// ---------------------------------------------------------------------------
// Workspace layout (peak ~169 MB):
//   [0)    ka 16M | [16M) va | [32M) ra (=sigmoid r)
//   [48M)  g2buf 16M (written by gemmF<2>; a2 round-trip eliminated)
//   [64M)  h8 (fp8 8M) -> reused as h28 (fp8, written by wkv3_gemm7)
//   [80M)  x1h 16M
//   [96M)  kk8 (fp8, 32M)
//   [128M) scan state: Sloc 2M | Zloc 2M | LprefS 2M | LprefZ 2M | TS 64K | TZ 64K
//   [160M) packed weights (~0.9 MB)
// ---------------------------------------------------------------------------
extern "C" void kernel_launch(void* const* d_in, const int* in_sizes, int n_in,
                              void* d_out, int out_size, void* d_ws, size_t ws_size,
                              hipStream_t stream) {
  const float* x     = (const float*)d_in[0];
  const float* Wk    = (const float*)d_in[1];
  const float* Wv    = (const float*)d_in[2];
  const float* Wr    = (const float*)d_in[3];
  const float* Wo    = (const float*)d_in[4];
  const float* Wkf   = (const float*)d_in[5];
  const float* Wvf   = (const float*)d_in[6];
  const float* Wrf   = (const float*)d_in[7];
  const float* g1    = (const float*)d_in[8];
  const float* b1    = (const float*)d_in[9];
  const float* g2    = (const float*)d_in[10];
  const float* b2    = (const float*)d_in[11];
  const float* decay = (const float*)d_in[12];
  const float* first = (const float*)d_in[13];
  float* out = (float*)d_out;
  char* ws = (char*)d_ws;

  __bf16* ka     = (__bf16*)(ws + 0);
  __bf16* va     = (__bf16*)(ws + 16777216LL);
  __bf16* ra     = (__bf16*)(ws + 33554432LL);
  __bf16* g2buf  = (__bf16*)(ws + 50331648LL);
  unsigned char* h8  = (unsigned char*)(ws + 67108864LL);
  unsigned char* h28 = (unsigned char*)(ws + 67108864LL);  // reuses h8 (dead)
  __bf16* x1h    = (__bf16*)(ws + 83886080LL);
  unsigned char* kk8 = (unsigned char*)(ws + 100663296LL);
  float*  Sloc   = (float*)(ws + 134217728LL);
  float*  Zloc   = (float*)(ws + 137363456LL);
  float*  LprefS = (float*)(ws + 140509184LL);
  float*  LprefZ = (float*)(ws + 143654912LL);
  float*  TS     = (float*)(ws + 146800640LL);
  float*  TZ     = (float*)(ws + 146866176LL);
  __bf16* WoT    = (__bf16*)(ws + 167772160LL);
  unsigned char* Wkvr8 = (unsigned char*)(ws + 167903232LL);
  unsigned char* Wkfr8 = (unsigned char*)(ws + 168099840LL);
  unsigned char* Wvf8  = (unsigned char*)(ws + 168427520LL);

  // --- prep: weight pack + LN1 in one launch ---
  prep<<<1024 + NTOK / 4, 256, 0, stream>>>(
      Wk, Wv, Wr, Wo, Wkf, Wvf, Wrf, WoT, Wkvr8, Wkfr8, Wvf8,
      x, g1, b1, h8);

  // --- SpatialMix ---
  gemmF<0, 6><<<512, 512, 0, stream>>>(h8, Wkvr8, ka, nullptr, nullptr);
  wkv_phase1<<<BDIM * NCHUNK / 4, 256, 0, stream>>>(ka, va, decay, Sloc, Zloc);
  wkv_phase2a<<<BDIM * NSEG, 256, 0, stream>>>(Sloc, Zloc, decay,
                                               LprefS, LprefZ, TS, TZ);
  // fused WKV output pass + (x + a2@Wo) + LN2 -> x1h, h28
  wkv3_gemm7<<<NTOK / 64, 256, 0, stream>>>(ka, va, ra, decay, first,
                                            LprefS, LprefZ, TS, TZ,
                                            WoT, x, g2, b2, x1h, h28);

  // --- ChannelMix ---
  gemmF<2, 10><<<512, 512, 0, stream>>>(h28, Wkfr8, nullptr, g2buf, kk8);
  gemm9<1024, 3><<<dim3(NTOK / 128, 2), 256, 0, stream>>>(
      kk8, Wvf8, NTOK, nullptr, nullptr, nullptr, out, x1h, g2buf);
}

// Round 11
// 239.114 us; speedup vs baseline: 1.0384x; 1.0384x over previous
//
#include <hip/hip_runtime.h>
#include <hip/hip_bf16.h>
#include <math.h>

// Problem constants
#define TDIM 4096
#define CDIM 256
#define BDIM 8
#define NTOK (BDIM * TDIM)   // 32768 rows
#define HIDDIM 1024
#define NCHUNK 256
#define CHLEN 16             // 4096 / 256
#define NSEG 8
#define SEGCH 32             // NCHUNK / NSEG

typedef float f32x4 __attribute__((ext_vector_type(4)));
typedef __bf16 bf16x8 __attribute__((ext_vector_type(8)));
typedef __bf16 bf16x4 __attribute__((ext_vector_type(4)));
typedef long long i64x2 __attribute__((ext_vector_type(2)));

// async global->LDS, 16 B/lane, lands at wave-uniform base + lane*16
#define GLDS16(gp, lp) __builtin_amdgcn_global_load_lds( \
    (const __attribute__((address_space(1))) void*)(gp), \
    (__attribute__((address_space(3))) void*)(lp), 16, 0, 0)

// s_waitcnt imm: vmcnt[3:0] in [3:0], expcnt [6:4], lgkm in [11:8], vmcnt[5:4] in [15:14]
#define WAITCNT_VM8  0x0F78
#define WAITCNT_VM5  0x0F75
#define WAITCNT_VM4  0x0F74
#define WAITCNT_VM2  0x0F72
#define WAITCNT_VM0  0x0F70
#define WAITCNT_LGKM0 0xC07F   // lgkmcnt(0) only; vmcnt/expcnt unconstrained

// LDS producer->consumer fence across waves: ds_writes must LAND before the
// barrier (raw s_barrier does NOT drain lgkmcnt — the r5 race).
#define STAGE_FENCE() do { \
    __builtin_amdgcn_sched_barrier(0); \
    __builtin_amdgcn_s_waitcnt(WAITCNT_LGKM0); \
    __builtin_amdgcn_s_barrier(); \
    __builtin_amdgcn_sched_barrier(0); \
  } while (0)

__device__ __forceinline__ float sigm(float v) { return 1.0f / (1.0f + __expf(-v)); }

// fp8 k-permutation within each 64-k group: k = p*64 + c*32 + q*8 + j
// -> byte position p*64 + q*16 + c*8 + j. A lane's b128 at row*64+q*16 then
// holds [chunk0 frag | chunk1 frag] for MFMA k=quad*8..+8 of both 32-chunks.
__device__ __forceinline__ int permk(int k) {
  return (k & ~63) + (((k >> 3) & 3) << 4) + (((k >> 5) & 1) << 3) + (k & 7);
}

// ---------------------------------------------------------------------------
// prep: merged weight-pack (blocks 0..1023) + LayerNorm1 (blocks 1024..9215).
// ---------------------------------------------------------------------------
__global__ __launch_bounds__(256) void prep(
    const float* __restrict__ Wk, const float* __restrict__ Wv,
    const float* __restrict__ Wr, const float* __restrict__ Wo,
    const float* __restrict__ Wkf, const float* __restrict__ Wvf,
    const float* __restrict__ Wrf,
    __bf16* __restrict__ WoT, unsigned char* __restrict__ Wkvr8,
    unsigned char* __restrict__ Wkfr8, unsigned char* __restrict__ Wvf8,
    const float* __restrict__ x, const float* __restrict__ gamma,
    const float* __restrict__ beta, unsigned char* __restrict__ h8) {
  if (blockIdx.x >= 1024) {
    // ---- LayerNorm over C=256: one wave per row ----
    const int wave = threadIdx.x >> 6, lane = threadIdx.x & 63;
    const long long row = (long long)(blockIdx.x - 1024) * 4 + wave;
    const long long base = row * CDIM + lane * 4;
    const f32x4 v = *(const f32x4*)&x[base];
    float s = v[0] + v[1] + v[2] + v[3];
    float s2 = v[0]*v[0] + v[1]*v[1] + v[2]*v[2] + v[3]*v[3];
    #pragma unroll
    for (int o = 1; o < 64; o <<= 1) { s += __shfl_xor(s, o); s2 += __shfl_xor(s2, o); }
    const float mean = s * (1.0f / CDIM);
    const float var = s2 * (1.0f / CDIM) - mean * mean;
    const float rstd = rsqrtf(var + 1e-5f);
    const f32x4 g4 = *(const f32x4*)&gamma[lane * 4];
    const f32x4 b4 = *(const f32x4*)&beta[lane * 4];
    float o0 = (v[0] - mean) * rstd * g4[0] + b4[0];
    float o1 = (v[1] - mean) * rstd * g4[1] + b4[1];
    float o2 = (v[2] - mean) * rstd * g4[2] + b4[2];
    float o3 = (v[3] - mean) * rstd * g4[3] + b4[3];
    int w = 0;
    w = __builtin_amdgcn_cvt_pk_fp8_f32(o0, o1, w, false);
    w = __builtin_amdgcn_cvt_pk_fp8_f32(o2, o3, w, true);
    *(int*)&h8[row * CDIM + permk(lane * 4)] = w;
    return;
  }
  long long j = (long long)blockIdx.x * 256 + threadIdx.x;
  if (j < 49152) {            // Wkvr8: 4 fp8/thread
    const long long d = j * 4;
    const int n = (int)(d >> 8), k0 = (int)(d & 255);
    const float* src = (n < 256) ? Wk : (n < 512 ? Wv : Wr);
    const int nn = n & 255;
    int w = 0;
    w = __builtin_amdgcn_cvt_pk_fp8_f32(src[k0 * 256 + nn],
                                        src[(k0 + 1) * 256 + nn], w, false);
    w = __builtin_amdgcn_cvt_pk_fp8_f32(src[(k0 + 2) * 256 + nn],
                                        src[(k0 + 3) * 256 + nn], w, true);
    *(int*)&Wkvr8[(long long)n * 256 + permk(k0)] = w;
    return;
  }
  j -= 49152;
  if (j < 65536) { int n = (int)(j >> 8), k = (int)(j & 255);
    WoT[j] = (__bf16)Wo[k * 256 + n]; return; }
  j -= 65536;
  if (j < 81920) {            // Wkfr8: 4 fp8/thread
    const long long d = j * 4;
    const int n = (int)(d >> 8), k0 = (int)(d & 255);
    float v0, v1, v2, v3;
    if (n < 1024) {
      v0 = Wkf[(long long)k0 * 1024 + n];       v1 = Wkf[(long long)(k0 + 1) * 1024 + n];
      v2 = Wkf[(long long)(k0 + 2) * 1024 + n]; v3 = Wkf[(long long)(k0 + 3) * 1024 + n];
    } else {
      const int m = n - 1024;
      v0 = Wrf[k0 * 256 + m];       v1 = Wrf[(k0 + 1) * 256 + m];
      v2 = Wrf[(k0 + 2) * 256 + m]; v3 = Wrf[(k0 + 3) * 256 + m];
    }
    int w = 0;
    w = __builtin_amdgcn_cvt_pk_fp8_f32(v0, v1, w, false);
    w = __builtin_amdgcn_cvt_pk_fp8_f32(v2, v3, w, true);
    *(int*)&Wkfr8[(long long)n * 256 + permk(k0)] = w;
    return;
  }
  j -= 81920;
  if (j < 65536) {            // Wvf8 [256][1024]: 4 fp8/thread
    const long long d = j * 4;
    const int n = (int)(d >> 10), k0 = (int)(d & 1023);
    int w = 0;
    w = __builtin_amdgcn_cvt_pk_fp8_f32(Wvf[(long long)k0 * 256 + n],
                                        Wvf[(long long)(k0 + 1) * 256 + n], w, false);
    w = __builtin_amdgcn_cvt_pk_fp8_f32(Wvf[(long long)(k0 + 2) * 256 + n],
                                        Wvf[(long long)(k0 + 3) * 256 + n], w, true);
    *(int*)&Wvf8[(long long)n * 1024 + permk(k0)] = w;
    return;
  }
}

// ---------------------------------------------------------------------------
// gemmF: K=256 fp8 GEMM, tile-streaming persistent structure.
//   r11: BM=64, 256 threads / 4 waves (1M x 4N), LDS 32 KB -> 4 blocks/CU
//   (was 2). Per-tile serial overhead (vmcnt+barrier+stage+fence+store) is
//   structural in a 2-phase schedule (m233); only co-resident independent
//   blocks can hide it (m114). Grid 1024, TPB = NTILES/1024.
//   T2 swizzle retained: GLDS source chunk (lane&3)^((lane>>3)&3), read
//   chunk quad^((mrow>>1)&3). B panel in regs (2 nt x 4 granules / wave).
// EPI 0: planar kvr store (plane = y>>1; 0:k 1:v 2:sigmoid->r)
// EPI 2: y<8: kk8 = fp8(relu(acc)^2) k-permuted [row stride 1024];
//        y>=8: g2 = sigmoid (bf16) [row stride 256]
// ---------------------------------------------------------------------------
template <int EPI, int NY>
__global__ __launch_bounds__(256, 4) void gemmF(
    const unsigned char* __restrict__ A8, const unsigned char* __restrict__ B8,
    __bf16* __restrict__ outH, __bf16* __restrict__ outH2,
    unsigned char* __restrict__ outC) {
  constexpr int NTILES = 512 * NY;          // BM=64 -> 512 m-tiles per y-panel
  constexpr int TPB = NTILES / 1024;
  static_assert(NTILES % 1024 == 0, "grid divisibility");
  __shared__ unsigned char sA[2][4 * 4096];   // [buf][granule g][row 0..63][64B]

  const int tid = threadIdx.x;
  const int wave = tid >> 6, lane = tid & 63;
  const int quad = lane >> 4, mrow = lane & 15;
  const int wn = wave * 32;                  // 4 waves x 32 cols = 128
  const int srow = lane >> 2;                // 0..15 (4 lanes per 64-B row)
  const int o16s = (((lane & 3) ^ ((lane >> 3) & 3)) << 4);  // swizzled src chunk
  const int rsw = (mrow >> 1) & 3;           // read-side swizzle
  const int t0 = blockIdx.x * TPB;

  // stage one A m-tile (64 rows x 256 B) into sA[buf]: 4 GLDS16/wave
  auto issueA = [&](int t, int buf) {
    const long long bm = (long long)(t & 511) * 64;
    const int r0 = wave * 16;
    #pragma unroll
    for (int g = 0; g < 4; g++)
      GLDS16(A8 + (bm + r0 + srow) * 256 + g * 64 + o16s,
             &sA[buf][g * 4096 + r0 * 64]);
  };

  // B panel in registers: 8 x b128 per wave (2 nt x 4 granules)
  i64x2 fb[2][4];
  auto loadB = [&](int y) {
    const long long bn = (long long)y * 128;
    #pragma unroll
    for (int nt = 0; nt < 2; nt++)
      #pragma unroll
      for (int g = 0; g < 4; g++)
        fb[nt][g] = *(const i64x2*)
            &B8[(bn + wn + nt * 16 + mrow) * 256 + g * 64 + quad * 16];
  };

  issueA(t0, 0);
  int prevy = -1;

  #pragma unroll 1
  for (int i = 0; i < TPB; i++) {
    const int t = t0 + i;
    const int y = t >> 9;
    const bool ych = (y != prevy);
    prevy = y;

    // A(t) landed (oldest vmem ops); prior-tile stores may stay in flight.
    if (i == 0)          __builtin_amdgcn_s_waitcnt(WAITCNT_VM0);
    else if (EPI == 0)   __builtin_amdgcn_s_waitcnt(WAITCNT_VM4);
    else                 __builtin_amdgcn_s_waitcnt(WAITCNT_VM2);
    __builtin_amdgcn_s_barrier();

    if (ych) loadB(y);                       // rare (y-panel boundary)
    if (i + 1 < TPB) issueA(t + 1, (i + 1) & 1);

    // ---- compute: full K=256 in one pass, 64 MFMA/wave ----
    f32x4 acc[4][2] = {};
    const int buf = i & 1;
    #pragma unroll
    for (int g = 0; g < 4; g++) {
      i64x2 fa[4];
      #pragma unroll
      for (int mt = 0; mt < 4; mt++)
        fa[mt] = *(const i64x2*)
            &sA[buf][g * 4096 + (mt * 16 + mrow) * 64 + ((quad ^ rsw) << 4)];
      #pragma unroll
      for (int c = 0; c < 2; c++)
        #pragma unroll
        for (int mt = 0; mt < 4; mt++)
          #pragma unroll
          for (int nt = 0; nt < 2; nt++)
            acc[mt][nt] = __builtin_amdgcn_mfma_f32_16x16x32_fp8_fp8(
                fb[nt][g][c], fa[mt][c], acc[mt][nt], 0, 0, 0);
    }

    // ---- staged epilogue: sA[buf] is dead; reuse as output staging ----
    __builtin_amdgcn_s_barrier();
    unsigned char* stg = &sA[buf][0];
    const long long bm = (long long)(t & 511) * 64;

    if (EPI == 0) {
      const int plane = y >> 1;
      // stage: [64 rows][256B bf16], XOR-swizzled 16B chunks
      #pragma unroll
      for (int mt = 0; mt < 4; mt++) {
        const int row = mt * 16 + mrow;
        const int swz = (row & 7) << 4;
        #pragma unroll
        for (int nt = 0; nt < 2; nt++) {
          const f32x4 a = acc[mt][nt];
          bf16x4 v;
          if (plane == 2) {
            #pragma unroll
            for (int r = 0; r < 4; r++) v[r] = (__bf16)sigm(a[r]);
          } else {
            #pragma unroll
            for (int r = 0; r < 4; r++) v[r] = (__bf16)a[r];
          }
          const int cb2 = (wn + nt * 16 + quad * 4) * 2;
          *(bf16x4*)&stg[row * 256 + (cb2 ^ swz)] = v;
        }
      }
      STAGE_FENCE();
      // write-out: 256 threads x 64B contiguous
      char* ob = (char*)(outH + (long long)plane * (32768LL * 256));
      const int row = tid >> 2, qb = (tid & 3) * 64;
      const int swz = (row & 7) << 4;
      const long long gb = (bm + row) * 512 + (long long)(y & 1) * 256 + qb;
      #pragma unroll
      for (int c = 0; c < 4; c++) {
        const i64x2 d = *(const i64x2*)&stg[row * 256 + ((qb + c * 16) ^ swz)];
        *(i64x2*)&ob[gb + c * 16] = d;
      }
    } else {
      if (y < 8) {
        // stage: [64 rows][128B fp8], permk within row, XOR-swizzled
        #pragma unroll
        for (int mt = 0; mt < 4; mt++) {
          const int row = mt * 16 + mrow;
          const int swz = (row & 7) << 4;
          #pragma unroll
          for (int nt = 0; nt < 2; nt++) {
            const f32x4 a = acc[mt][nt];
            float q0 = a[0] > 0.0f ? a[0] : 0.0f;
            float q1 = a[1] > 0.0f ? a[1] : 0.0f;
            float q2 = a[2] > 0.0f ? a[2] : 0.0f;
            float q3 = a[3] > 0.0f ? a[3] : 0.0f;
            int w = 0;
            w = __builtin_amdgcn_cvt_pk_fp8_f32(q0 * q0, q1 * q1, w, false);
            w = __builtin_amdgcn_cvt_pk_fp8_f32(q2 * q2, q3 * q3, w, true);
            const int cbl = wn + nt * 16 + quad * 4;      // tile-local col
            *(int*)&stg[row * 128 + (permk(cbl) ^ swz)] = w;
          }
        }
        STAGE_FENCE();
        // write-out: 256 threads x 32B contiguous
        const int row = tid >> 2, sb = (tid & 3) * 32;
        const int swz = (row & 7) << 4;
        const long long gb = (bm + row) * 1024 + (long long)y * 128 + sb;
        #pragma unroll
        for (int c = 0; c < 2; c++) {
          const i64x2 d = *(const i64x2*)&stg[row * 128 + ((sb + c * 16) ^ swz)];
          *(i64x2*)&outC[gb + c * 16] = d;
        }
      } else {
        // stage: [64 rows][256B bf16]
        #pragma unroll
        for (int mt = 0; mt < 4; mt++) {
          const int row = mt * 16 + mrow;
          const int swz = (row & 7) << 4;
          #pragma unroll
          for (int nt = 0; nt < 2; nt++) {
            const f32x4 a = acc[mt][nt];
            bf16x4 v;
            #pragma unroll
            for (int r = 0; r < 4; r++) v[r] = (__bf16)sigm(a[r]);
            const int cb2 = (wn + nt * 16 + quad * 4) * 2;
            *(bf16x4*)&stg[row * 256 + (cb2 ^ swz)] = v;
          }
        }
        STAGE_FENCE();
        char* ob = (char*)outH2;
        const int row = tid >> 2, qb = (tid & 3) * 64;
        const int swz = (row & 7) << 4;
        const long long gb = (bm + row) * 512 + (long long)(y - 8) * 256 + qb;
        #pragma unroll
        for (int c = 0; c < 4; c++) {
          const i64x2 d = *(const i64x2*)&stg[row * 256 + ((qb + c * 16) ^ swz)];
          *(i64x2*)&ob[gb + c * 16] = d;
        }
      }
    }
  }
}

// ---------------------------------------------------------------------------
// fp8 MFMA GEMM with k-permuted operands (K=1024, EPI 3 only).
// r10 T2 swizzle retained on sA and sB.
// ---------------------------------------------------------------------------
template <int K, int EPI>
__global__ __launch_bounds__(256, 3) void gemm9(
    const unsigned char* __restrict__ A8, const unsigned char* __restrict__ B8,
    int M, __bf16* __restrict__ outH, __bf16* __restrict__ outH2,
    unsigned char* __restrict__ outC,
    float* __restrict__ outF, const __bf16* __restrict__ srcH,
    const __bf16* __restrict__ gate) {
  constexpr int NIT = K / 64;
  __shared__ unsigned char sA[3][128 * 64];
  __shared__ unsigned char sB[3][128 * 64];
  const int tid = threadIdx.x;
  const int wave = tid >> 6, lane = tid & 63;
  const int quad = lane >> 4, mrow = lane & 15;
  const long long bm = (long long)blockIdx.x * 128;
  const long long bn = (long long)blockIdx.y * 128;
  const int wm = (wave & 1) * 64, wn = (wave >> 1) * 64;
  const int srow = lane >> 2;          // 0..15 (4 lanes per 64-B row)
  const int o16s = (((lane & 3) ^ ((lane >> 3) & 3)) << 4);
  const int rsw = (mrow >> 1) & 3;

  auto issue = [&](int g) {
    const int buf = g % 3;
    const long long k0 = (long long)g * 64;
    const int a0 = wave * 32;
    GLDS16(A8 + (bm + a0 + srow) * (long long)K + k0 + o16s, &sA[buf][a0 * 64]);
    GLDS16(A8 + (bm + a0 + 16 + srow) * (long long)K + k0 + o16s, &sA[buf][(a0 + 16) * 64]);
    GLDS16(B8 + (bn + a0 + srow) * (long long)K + k0 + o16s, &sB[buf][a0 * 64]);
    GLDS16(B8 + (bn + a0 + 16 + srow) * (long long)K + k0 + o16s, &sB[buf][(a0 + 16) * 64]);
  };

  f32x4 acc[4][4] = {};
  issue(0);
  if (NIT > 1) issue(1);

  auto compute = [&](int g) {
    const int buf = g % 3;
    i64x2 fa[4], fb[4];
    #pragma unroll
    for (int mt = 0; mt < 4; mt++)
      fa[mt] = *(const i64x2*)&sA[buf][(wm + mt * 16 + mrow) * 64 + ((quad ^ rsw) << 4)];
    #pragma unroll
    for (int nt = 0; nt < 4; nt++)
      fb[nt] = *(const i64x2*)&sB[buf][(wn + nt * 16 + mrow) * 64 + ((quad ^ rsw) << 4)];
    #pragma unroll
    for (int c = 0; c < 2; c++)
      #pragma unroll
      for (int mt = 0; mt < 4; mt++)
        #pragma unroll
        for (int nt = 0; nt < 4; nt++)
          acc[mt][nt] = __builtin_amdgcn_mfma_f32_16x16x32_fp8_fp8(
              fb[nt][c], fa[mt][c], acc[mt][nt], 0, 0, 0);
  };

  #pragma unroll 1
  for (int g = 0; g < NIT; g++) {
    if (g == NIT - 1) {
      __builtin_amdgcn_s_waitcnt(WAITCNT_VM0);
    } else {
      __builtin_amdgcn_s_waitcnt(WAITCNT_VM4);
    }
    __builtin_amdgcn_s_barrier();
    if (g + 2 < NIT) issue(g + 2);
    compute(g);
  }

  #pragma unroll
  for (int mt = 0; mt < 4; mt++) {
    #pragma unroll
    for (int nt = 0; nt < 4; nt++) {
      const long long row = bm + wm + mt * 16 + mrow;
      const long long colb = bn + wn + nt * 16 + quad * 4;
      const f32x4 a = acc[mt][nt];
      const long long idx = row * 256 + colb;
      const bf16x4 s4 = *(const bf16x4*)&srcH[idx];
      const bf16x4 g4 = *(const bf16x4*)&gate[idx];
      f32x4 v;
      #pragma unroll
      for (int r = 0; r < 4; r++) v[r] = (float)s4[r] + (float)g4[r] * a[r];
      *(f32x4*)&outF[idx] = v;
    }
  }
}

// ---------------------------------------------------------------------------
// WKV phases 1 & 2a — identical to r7/r9 (passing).
// ---------------------------------------------------------------------------
__global__ __launch_bounds__(256) void wkv_phase1(
    const __bf16* __restrict__ ka, const __bf16* __restrict__ va,
    const float* __restrict__ decay,
    float* __restrict__ Sloc, float* __restrict__ Zloc) {
  const int wave = threadIdx.x >> 6, lane = threadIdx.x & 63;
  const int gi = blockIdx.x * 4 + wave;          // 0..2047
  const int b = gi >> 8, chunk = gi & (NCHUNK - 1);
  const int c0 = lane * 4;
  const f32x4 w4 = *(const f32x4*)&decay[c0];
  f32x4 ew;
  #pragma unroll
  for (int r = 0; r < 4; r++) ew[r] = __expf(w4[r] * (1.0f / TDIM));
  f32x4 S = {0,0,0,0}, Z = {0,0,0,0};
  long long base = ((long long)b * TDIM + (long long)chunk * CHLEN) * 256 + c0;
  #pragma unroll 4
  for (int t = 0; t < CHLEN; t++) {
    const bf16x4 k4 = *(const bf16x4*)&ka[base + (long long)t * 256];
    const bf16x4 v4 = *(const bf16x4*)&va[base + (long long)t * 256];
    #pragma unroll
    for (int r = 0; r < 4; r++) {
      const float ek = __expf((float)k4[r]);
      S[r] = ew[r] * S[r] + ek * (float)v4[r];
      Z[r] = ew[r] * Z[r] + ek;
    }
  }
  const long long o = (long long)gi * 256 + c0;
  *(f32x4*)&Sloc[o] = S;
  *(f32x4*)&Zloc[o] = Z;
}

__global__ __launch_bounds__(256) void wkv_phase2a(
    const float* __restrict__ Sloc, const float* __restrict__ Zloc,
    const float* __restrict__ decay,
    float* __restrict__ LprefS, float* __restrict__ LprefZ,
    float* __restrict__ TS, float* __restrict__ TZ) {
  const int b = blockIdx.x >> 3, seg = blockIdx.x & 7;   // 64 blocks
  const int c = threadIdx.x;                             // one channel/thread
  const float w = decay[c] * (1.0f / TDIM);
  const float ewL = __expf(w * (float)CHLEN);
  float S = 0.0f, Z = 0.0f;
  long long o = ((long long)(b * NCHUNK + seg * SEGCH)) * 256 + c;
  #pragma unroll 4
  for (int i = 0; i < SEGCH; i++, o += 256) {
    LprefS[o] = S;
    LprefZ[o] = Z;
    S = ewL * S + Sloc[o];
    Z = ewL * Z + Zloc[o];
  }
  const int to = (b * NSEG + seg) * 256 + c;
  TS[to] = S;
  TZ[to] = Z;
}

// ---------------------------------------------------------------------------
// wkv3_gemm7: FUSED wkv_phase3 + gemm7 (r9/r10 structure, passing).
// ---------------------------------------------------------------------------
__global__ __launch_bounds__(256, 2) void wkv3_gemm7(
    const __bf16* __restrict__ ka, const __bf16* __restrict__ va,
    const __bf16* __restrict__ ra,   // holds sigmoid(r)
    const float* __restrict__ decay, const float* __restrict__ first,
    const float* __restrict__ LprefS, const float* __restrict__ LprefZ,
    const float* __restrict__ TS, const float* __restrict__ TZ,
    const __bf16* __restrict__ Bt,   // WoT [256][256]
    const float* __restrict__ x,
    const float* __restrict__ gammaP, const float* __restrict__ betaP,
    __bf16* __restrict__ x1h, unsigned char* __restrict__ h28) {
  __shared__ __bf16 sA2[8 * 64 * 32];         // 32 KB, [g][row][32 bf16]
  __shared__ __bf16 sB[2][256 * 32];          // 32 KB
  __shared__ float redS[4][64], redQ[4][64];  // 2 KB

  const int tid = threadIdx.x;
  const int wave = tid >> 6, lane = tid & 63;
  const int quad = lane >> 4, mrow = lane & 15;
  const long long bm = (long long)blockIdx.x * 64;
  const int wn = wave * 64;
  const int lrow = lane >> 2;
  const int lks = ((lane & 3) ^ ((lane >> 3) & 3)) * 8;   // swizzled src (bf16 units)
  const int rsw = (mrow >> 1) & 3;

  // B staging (WoT only; A comes from LDS)
  auto issue = [&](int g) {
    const int buf = g & 1;
    const long long k0 = (long long)g * 32;
    #pragma unroll
    for (int bc = 0; bc < 4; bc++) {
      const int r0 = wave * 64 + bc * 16;
      GLDS16(Bt + (r0 + lrow) * 256 + k0 + lks, &sB[buf][r0 * 32]);
    }
  };
  issue(0);    // lands during Phase A

  // ===== Phase A: WKV output pass for this wave's chunk -> sA2 =====
  {
    const int gi = blockIdx.x * 4 + wave;          // 0..2047
    const int b = gi >> 8, chunk = gi & (NCHUNK - 1);
    const int seg = chunk >> 5, d = chunk & (SEGCH - 1);
    const int c0 = lane * 4;
    const f32x4 w4 = *(const f32x4*)&decay[c0];
    const f32x4 u4 = *(const f32x4*)&first[c0];
    f32x4 ew, eu;
    #pragma unroll
    for (int r = 0; r < 4; r++) {
      ew[r] = __expf(w4[r] * (1.0f / TDIM));
      eu[r] = __expf(u4[r] * (1.0f / TDIM));
    }
    const long long so = (long long)gi * 256 + c0;
    const f32x4 Lp = *(const f32x4*)&LprefS[so];
    const f32x4 LpZ = *(const f32x4*)&LprefZ[so];
    f32x4 S, Z;
    #pragma unroll
    for (int r = 0; r < 4; r++) {
      const float wr = w4[r] * (1.0f / TDIM);
      const float ew32 = __expf(wr * (float)(CHLEN * SEGCH));
      float CS = 0.0f, CZ = 0.0f;
      const int tb = b * NSEG * 256 + c0 + r;
      for (int s = 0; s < seg; s++) {
        CS = ew32 * CS + TS[tb + s * 256];
        CZ = ew32 * CZ + TZ[tb + s * 256];
      }
      const float f0 = __expf(wr * (float)(CHLEN * d));
      S[r] = f0 * CS + Lp[r];
      Z[r] = f0 * CZ + LpZ[r];
    }
    long long gbase = ((long long)b * TDIM + (long long)chunk * CHLEN) * 256 + c0;
    const int abase = (lane >> 3) * 2048 + (wave * 16) * 32;
    const int cch = (lane >> 1) & 3;
    const int half4 = (lane & 1) * 4;
    #pragma unroll 2
    for (int t = 0; t < CHLEN; t++) {
      const long long p = gbase + (long long)t * 256;
      const bf16x4 k4 = *(const bf16x4*)&ka[p];
      const bf16x4 v4 = *(const bf16x4*)&va[p];
      const bf16x4 r4 = *(const bf16x4*)&ra[p];
      bf16x4 o;
      #pragma unroll
      for (int r = 0; r < 4; r++) {
        const float ek = __expf((float)k4[r]);
        const float E = eu[r] * ek;
        const float y = (S[r] + E * (float)v4[r]) / (Z[r] + E);
        o[r] = (__bf16)((float)r4[r] * y);
        S[r] = ew[r] * S[r] + ek * (float)v4[r];
        Z[r] = ew[r] * Z[r] + ek;
      }
      *(bf16x4*)&sA2[abase + t * 32 + ((cch ^ ((t >> 1) & 3)) * 8 + half4)] = o;
    }
  }
  __syncthreads();   // full fence: sA2 visible to all waves

  // ===== Phase B: gemm7 K-loop (A from sA2, B from GLDS-staged sB) =====
  f32x4 acc[4][4] = {};

  auto compute = [&](int g) {
    const int buf = g & 1;
    bf16x8 fa[4], fb[4];
    #pragma unroll
    for (int mt = 0; mt < 4; mt++)
      fa[mt] = *(const bf16x8*)&sA2[g * 2048 + (mt * 16 + mrow) * 32 + (quad ^ rsw) * 8];
    #pragma unroll
    for (int nt = 0; nt < 4; nt++)
      fb[nt] = *(const bf16x8*)&sB[buf][(wn + nt * 16 + mrow) * 32 + (quad ^ rsw) * 8];
    #pragma unroll
    for (int mt = 0; mt < 4; mt++)
      #pragma unroll
      for (int nt = 0; nt < 4; nt++)
        acc[mt][nt] = __builtin_amdgcn_mfma_f32_16x16x32_bf16(fb[nt], fa[mt], acc[mt][nt], 0, 0, 0);
  };

  #pragma unroll 1
  for (int g = 0; g < 8; g++) {
    __builtin_amdgcn_s_waitcnt(WAITCNT_VM0);   // issue(g) landed (posted 1 iter ago)
    __builtin_amdgcn_s_barrier();              // all waves done reading buf (g+1)&1
    if (g + 1 < 8) issue(g + 1);
    compute(g);
  }

  // residual add + LN partials
  float sum[4] = {0, 0, 0, 0}, sq[4] = {0, 0, 0, 0};
  #pragma unroll
  for (int mt = 0; mt < 4; mt++) {
    #pragma unroll
    for (int nt = 0; nt < 4; nt++) {
      const long long row = bm + mt * 16 + mrow;
      const long long colb = wn + nt * 16 + quad * 4;
      acc[mt][nt] += *(const f32x4*)&x[row * 256 + colb];
      #pragma unroll
      for (int r = 0; r < 4; r++) {
        sum[mt] += acc[mt][nt][r];
        sq[mt] += acc[mt][nt][r] * acc[mt][nt][r];
      }
    }
  }
  #pragma unroll
  for (int mt = 0; mt < 4; mt++) {
    sum[mt] += __shfl_xor(sum[mt], 16); sq[mt] += __shfl_xor(sq[mt], 16);
    sum[mt] += __shfl_xor(sum[mt], 32); sq[mt] += __shfl_xor(sq[mt], 32);
  }
  if (quad == 0) {
    #pragma unroll
    for (int mt = 0; mt < 4; mt++) {
      redS[wave][mt * 16 + mrow] = sum[mt];
      redQ[wave][mt * 16 + mrow] = sq[mt];
    }
  }
  __syncthreads();
  #pragma unroll
  for (int mt = 0; mt < 4; mt++) {
    const int rb = mt * 16 + mrow;
    const float ts = redS[0][rb] + redS[1][rb] + redS[2][rb] + redS[3][rb];
    const float tq = redQ[0][rb] + redQ[1][rb] + redQ[2][rb] + redQ[3][rb];
    const float mean = ts * (1.0f / 256.0f);
    const float rstd = rsqrtf(tq * (1.0f / 256.0f) - mean * mean + 1e-5f);
    const long long row = bm + rb;
    #pragma unroll
    for (int nt = 0; nt < 4; nt++) {
      const long long colb = wn + nt * 16 + quad * 4;
      const f32x4 g4 = *(const f32x4*)&gammaP[colb];
      const f32x4 b4 = *(const f32x4*)&betaP[colb];
      bf16x4 xo;
      const float t0 = acc[mt][nt][0], t1 = acc[mt][nt][1];
      const float t2 = acc[mt][nt][2], t3 = acc[mt][nt][3];
      xo[0] = (__bf16)t0; xo[1] = (__bf16)t1; xo[2] = (__bf16)t2; xo[3] = (__bf16)t3;
      const float h0 = (t0 - mean) * rstd * g4[0] + b4[0];
      const float h1 = (t1 - mean) * rstd * g4[1] + b4[1];
      const float h2v = (t2 - mean) * rstd * g4[2] + b4[2];
      const float h3 = (t3 - mean) * rstd * g4[3] + b4[3];
      *(bf16x4*)&x1h[row * 256 + colb] = xo;
      int w = 0;
      w = __builtin_amdgcn_cvt_pk_fp8_f32(h0, h1, w, false);
      w = __builtin_amdgcn_cvt_pk_fp8_f32(h2v, h3, w, true);
      *(int*)&h28[row * 256 + permk((int)colb)] = w;
    }
  }
}

// ---------------------------------------------------------------------------
// Workspace layout (peak ~169 MB):
//   [0)    ka 16M | [16M) va | [32M) ra (=sigmoid r)
//   [48M)  g2buf 16M (written by gemmF<2>; a2 round-trip eliminated)
//   [64M)  h8 (fp8 8M) -> reused as h28 (fp8, written by wkv3_gemm7)
//   [80M)  x1h 16M
//   [96M)  kk8 (fp8, 32M)
//   [128M) scan state: Sloc 2M | Zloc 2M | LprefS 2M | LprefZ 2M | TS 64K | TZ 64K
//   [160M) packed weights (~0.9 MB)
// ---------------------------------------------------------------------------
extern "C" void kernel_launch(void* const* d_in, const int* in_sizes, int n_in,
                              void* d_out, int out_size, void* d_ws, size_t ws_size,
                              hipStream_t stream) {
  const float* x     = (const float*)d_in[0];
  const float* Wk    = (const float*)d_in[1];
  const float* Wv    = (const float*)d_in[2];
  const float* Wr    = (const float*)d_in[3];
  const float* Wo    = (const float*)d_in[4];
  const float* Wkf   = (const float*)d_in[5];
  const float* Wvf   = (const float*)d_in[6];
  const float* Wrf   = (const float*)d_in[7];
  const float* g1    = (const float*)d_in[8];
  const float* b1    = (const float*)d_in[9];
  const float* g2    = (const float*)d_in[10];
  const float* b2    = (const float*)d_in[11];
  const float* decay = (const float*)d_in[12];
  const float* first = (const float*)d_in[13];
  float* out = (float*)d_out;
  char* ws = (char*)d_ws;

  __bf16* ka     = (__bf16*)(ws + 0);
  __bf16* va     = (__bf16*)(ws + 16777216LL);
  __bf16* ra     = (__bf16*)(ws + 33554432LL);
  __bf16* g2buf  = (__bf16*)(ws + 50331648LL);
  unsigned char* h8  = (unsigned char*)(ws + 67108864LL);
  unsigned char* h28 = (unsigned char*)(ws + 67108864LL);  // reuses h8 (dead)
  __bf16* x1h    = (__bf16*)(ws + 83886080LL);
  unsigned char* kk8 = (unsigned char*)(ws + 100663296LL);
  float*  Sloc   = (float*)(ws + 134217728LL);
  float*  Zloc   = (float*)(ws + 137363456LL);
  float*  LprefS = (float*)(ws + 140509184LL);
  float*  LprefZ = (float*)(ws + 143654912LL);
  float*  TS     = (float*)(ws + 146800640LL);
  float*  TZ     = (float*)(ws + 146866176LL);
  __bf16* WoT    = (__bf16*)(ws + 167772160LL);
  unsigned char* Wkvr8 = (unsigned char*)(ws + 167903232LL);
  unsigned char* Wkfr8 = (unsigned char*)(ws + 168099840LL);
  unsigned char* Wvf8  = (unsigned char*)(ws + 168427520LL);

  // --- prep: weight pack + LN1 in one launch ---
  prep<<<1024 + NTOK / 4, 256, 0, stream>>>(
      Wk, Wv, Wr, Wo, Wkf, Wvf, Wrf, WoT, Wkvr8, Wkfr8, Wvf8,
      x, g1, b1, h8);

  // --- SpatialMix ---
  gemmF<0, 6><<<1024, 256, 0, stream>>>(h8, Wkvr8, ka, nullptr, nullptr);
  wkv_phase1<<<BDIM * NCHUNK / 4, 256, 0, stream>>>(ka, va, decay, Sloc, Zloc);
  wkv_phase2a<<<BDIM * NSEG, 256, 0, stream>>>(Sloc, Zloc, decay,
                                               LprefS, LprefZ, TS, TZ);
  // fused WKV output pass + (x + a2@Wo) + LN2 -> x1h, h28
  wkv3_gemm7<<<NTOK / 64, 256, 0, stream>>>(ka, va, ra, decay, first,
                                            LprefS, LprefZ, TS, TZ,
                                            WoT, x, g2, b2, x1h, h28);

  // --- ChannelMix ---
  gemmF<2, 10><<<1024, 256, 0, stream>>>(h28, Wkfr8, nullptr, g2buf, kk8);
  gemm9<1024, 3><<<dim3(NTOK / 128, 2), 256, 0, stream>>>(
      kk8, Wvf8, NTOK, nullptr, nullptr, nullptr, out, x1h, g2buf);
}